// Round 7
// baseline (1011.063 us; speedup 1.0000x reference)
//
#include <hip/hip_runtime.h>
#include <stdint.h>

// y[m,o] = sum_k x[m,k]*(W8[o,k]-zero[o])*scale[o] + bias[o], M=8192 N=11008 K=4096.
// x ~= xs_m*(128*h + l) (h,l int8); G = xs_m*(128*Gh + Gl) via two i8 MFMA GEMMs
// sharing B-frags; y = scale*G - scale*zero*rowsum + bias.
// R7: NO LDS in the GEMM. A (x_h/x_l) and B (W) are pre-swizzled by the prep
// kernels into fragment-major layout [panel][K/16 chunk][16 rows][16B] so each
// wave's 16x16x64 MFMA fragment is ONE coalesced 1024B global_load_dwordx4
// (lane addr = panel*65536 + (c0+g)*256 + fr*16). Reuse via L1/L2 (sibling
// waves issue identical addresses; one bare s_barrier/tile keeps them aligned).
// Ping-pong register half-tile sets; loads for half h+1 issue before MFMA of h.

#define M_DIM 8192
#define N_DIM 11008
#define K_DIM 4096
#define NT    (K_DIM / 128)   // 32 K-tiles of BK=128 (2 halves of 64)

typedef __attribute__((ext_vector_type(4))) int i32x4;

// ---------------- prep kernels ----------------

// W int32 (int8-valued) [N][K] -> fragment layout Wq[q][c][r][16]:
// q = o>>4, r = o&15, c = k>>4. grid = N/16 = 688, block 256.
__global__ __launch_bounds__(256) void convert_w_kernel(
    const int* __restrict__ w, int8_t* __restrict__ Wq) {
  const int q = blockIdx.x;
  const int r = threadIdx.x & 15;
  const int cg = threadIdx.x >> 4;          // 0..15, handles chunks cg*16..+15
  const int o = q * 16 + r;
  const int4* src = (const int4*)(w + (size_t)o * K_DIM + cg * 256);
  int8_t* dst = Wq + (size_t)q * 65536 + (size_t)(cg * 16) * 256 + r * 16;
  #pragma unroll 4
  for (int jc = 0; jc < 16; ++jc) {
    int4 o4;
    int4 v0 = src[jc * 4 + 0], v1 = src[jc * 4 + 1];
    int4 v2 = src[jc * 4 + 2], v3 = src[jc * 4 + 3];
    o4.x = (v0.x & 255) | ((v0.y & 255) << 8) | ((v0.z & 255) << 16) | ((v0.w & 255) << 24);
    o4.y = (v1.x & 255) | ((v1.y & 255) << 8) | ((v1.z & 255) << 16) | ((v1.w & 255) << 24);
    o4.z = (v2.x & 255) | ((v2.y & 255) << 8) | ((v2.z & 255) << 16) | ((v2.w & 255) << 24);
    o4.w = (v3.x & 255) | ((v3.y & 255) << 8) | ((v3.z & 255) << 16) | ((v3.w & 255) << 24);
    *(int4*)(dst + jc * 256) = o4;
  }
}

// x [M][K] fp32 -> per-row stats (xs, rsum) + h/l int8 in fragment layout
// Axq[p][c][r][16], p = m>>4, r = m&15, c = k>>4. grid = M/16 = 512, block 256.
__global__ __launch_bounds__(256) void quantx_kernel(
    const float* __restrict__ x, int8_t* __restrict__ Axh, int8_t* __restrict__ Axl,
    float* __restrict__ xs, float* __restrict__ rsum) {
  const int p = blockIdx.x;
  const int r = threadIdx.x & 15;
  const int cg = threadIdx.x >> 4;          // 0..15
  const int row = p * 16 + r;
  const float4* px = (const float4*)(x + (size_t)row * K_DIM + cg * 256);

  // phase 1: partial max/sum over this thread's 256 floats
  float mx = 0.f, sm = 0.f;
  #pragma unroll 8
  for (int j = 0; j < 64; ++j) {
    float4 v = px[j];
    mx = fmaxf(mx, fmaxf(fmaxf(fabsf(v.x), fabsf(v.y)), fmaxf(fabsf(v.z), fabsf(v.w))));
    sm += v.x + v.y + v.z + v.w;
  }
  __shared__ float s_mx[16][16], s_sm[16][16];
  s_mx[cg][r] = mx; s_sm[cg][r] = sm;
  __syncthreads();
  float rowmax = 0.f, rowsumv = 0.f;
  #pragma unroll
  for (int k = 0; k < 16; ++k) {
    rowmax = fmaxf(rowmax, s_mx[k][r]);
    rowsumv += s_sm[k][r];
  }
  if (cg == 0) {
    xs[row] = rowmax > 0.f ? rowmax / 16256.f : 0.f;
    rsum[row] = rowsumv;
  }
  const float inv = rowmax > 0.f ? 16256.f / rowmax : 0.f;

  // phase 2: quantize (re-read from L2), write fragment-major
  int8_t* dh = Axh + (size_t)p * 65536 + (size_t)(cg * 16) * 256 + r * 16;
  int8_t* dl = Axl + (size_t)p * 65536 + (size_t)(cg * 16) * 256 + r * 16;
  #pragma unroll 2
  for (int jc = 0; jc < 16; ++jc) {
    int4 hw, lw;
    #pragma unroll
    for (int u = 0; u < 4; ++u) {
      float4 v = px[jc * 4 + u];
      int q0 = (int)rintf(v.x * inv), q1 = (int)rintf(v.y * inv);
      int q2 = (int)rintf(v.z * inv), q3 = (int)rintf(v.w * inv);
      int h0 = (q0 + 64) >> 7, h1 = (q1 + 64) >> 7, h2 = (q2 + 64) >> 7, h3 = (q3 + 64) >> 7;
      int l0 = q0 - (h0 << 7), l1 = q1 - (h1 << 7), l2 = q2 - (h2 << 7), l3 = q3 - (h3 << 7);
      ((int*)&hw)[u] = (h0 & 255) | ((h1 & 255) << 8) | ((h2 & 255) << 16) | ((h3 & 255) << 24);
      ((int*)&lw)[u] = (l0 & 255) | ((l1 & 255) << 8) | ((l2 & 255) << 16) | ((l3 & 255) << 24);
    }
    *(int4*)(dh + jc * 256) = hw;
    *(int4*)(dl + jc * 256) = lw;
  }
}

// ---------------- main GEMM (LDS-free, direct-to-reg fragments) ----------------

__global__ __launch_bounds__(512, 2) void qgemm_kernel(
    const int8_t* __restrict__ Axh, const int8_t* __restrict__ Axl,
    const int8_t* __restrict__ Wq, const float* __restrict__ xs,
    const float* __restrict__ rowsum, const float* __restrict__ scale,
    const float* __restrict__ zero, const float* __restrict__ bias,
    float* __restrict__ out) {
  const int tid = threadIdx.x;
  const int wave = tid >> 6;
  const int lane = tid & 63;

  // XCD-chunked + grouped mapping: nwg=2752=8*344; each XCD gets an 8-bm strip.
  const int bid = blockIdx.x;
  const int wg = (bid & 7) * 344 + (bid >> 3);
  const int group = wg / 344;
  const int rem = wg % 344;
  const int bm = group * 8 + (rem & 7);  // 0..63 (M/128)
  const int bn = rem >> 3;               // 0..42 (N/256)

  const int wr = wave >> 2;  // 0..1: 64-row half of 128
  const int wc = wave & 3;   // 0..3: 64-col quarter of 256

  const int fr = lane & 15;
  const int g = lane >> 4;
  const uint32_t laneoff = (uint32_t)(g * 256 + fr * 16);

  uint32_t pa[4], pb[4];
  #pragma unroll
  for (int mi = 0; mi < 4; ++mi) pa[mi] = (uint32_t)(bm * 8 + wr * 4 + mi) * 65536u + laneoff;
  #pragma unroll
  for (int ni = 0; ni < 4; ++ni) pb[ni] = (uint32_t)(bn * 16 + wc * 4 + ni) * 65536u + laneoff;

  i32x4 acch[4][4], accl[4][4];
  #pragma unroll
  for (int i = 0; i < 4; ++i)
    #pragma unroll
    for (int j = 0; j < 4; ++j) {
      acch[i][j] = (i32x4){0, 0, 0, 0};
      accl[i][j] = (i32x4){0, 0, 0, 0};
    }

#define LOADH(cb, ah, al, bf) do {                                        \
    _Pragma("unroll")                                                     \
    for (int mi = 0; mi < 4; ++mi) {                                      \
      ah[mi] = *(const i32x4*)(Axh + pa[mi] + (cb));                      \
      al[mi] = *(const i32x4*)(Axl + pa[mi] + (cb));                      \
    }                                                                     \
    _Pragma("unroll")                                                     \
    for (int ni = 0; ni < 4; ++ni)                                        \
      bf[ni] = *(const i32x4*)(Wq + pb[ni] + (cb));                       \
  } while (0)

#define MMH(ah, al, bf) do {                                              \
    __builtin_amdgcn_s_setprio(1);                                        \
    _Pragma("unroll")                                                     \
    for (int mi = 0; mi < 4; ++mi)                                        \
      _Pragma("unroll")                                                   \
      for (int ni = 0; ni < 4; ++ni) {                                    \
        acch[mi][ni] = __builtin_amdgcn_mfma_i32_16x16x64_i8(ah[mi], bf[ni], acch[mi][ni], 0, 0, 0); \
        accl[mi][ni] = __builtin_amdgcn_mfma_i32_16x16x64_i8(al[mi], bf[ni], accl[mi][ni], 0, 0, 0); \
      }                                                                   \
    __builtin_amdgcn_s_setprio(0);                                        \
  } while (0)

  i32x4 ah0[4], al0[4], bf0[4], ah1[4], al1[4], bf1[4];

  // prologue: half 0 of tile 0  (half h of tile t lives at byte cb = t*2048 + h*1024)
  LOADH(0u, ah0, al0, bf0);

  #pragma unroll 1
  for (int t = 0; t < NT; ++t) {
    const uint32_t cb1 = (uint32_t)t * 2048u + 1024u;
    LOADH(cb1, ah1, al1, bf1);   // issue half-1 loads before half-0 MFMAs
    MMH(ah0, al0, bf0);
    if (t + 1 < NT) {
      const uint32_t cb2 = (uint32_t)(t + 1) * 2048u;
      LOADH(cb2, ah0, al0, bf0); // issue next-tile half-0 before half-1 MFMAs
    }
    MMH(ah1, al1, bf1);
    __builtin_amdgcn_s_barrier();  // bare sync: keep sibling waves L1-aligned
  }

#undef LOADH
#undef MMH

  // epilogue: G = xs_m*(128*Gh + Gl); y = scale*G - scale*zero*rowsum + bias
  // C/D 16x16 layout: col = lane&15, row = (lane>>4)*4 + j
  const int row0 = bm * 128 + wr * 64;
  const int col0 = bn * 256 + wc * 64;
  float s_[4], sz_[4], b_[4];
  #pragma unroll
  for (int ni = 0; ni < 4; ++ni) {
    const int n = col0 + ni * 16 + fr;
    const float s = scale[n];
    s_[ni] = s;
    sz_[ni] = s * zero[n];
    b_[ni] = bias[n];
  }
  #pragma unroll
  for (int mi = 0; mi < 4; ++mi) {
    #pragma unroll
    for (int j = 0; j < 4; ++j) {
      const int m = row0 + mi * 16 + g * 4 + j;
      const float xsm = xs[m];
      const float rs = rowsum[m];
      float* po = out + (size_t)m * N_DIM + col0;
      #pragma unroll
      for (int ni = 0; ni < 4; ++ni) {
        const float G = xsm * (128.f * (float)acch[mi][ni][j] + (float)accl[mi][ni][j]);
        po[ni * 16 + fr] = s_[ni] * G - sz_[ni] * rs + b_[ni];
      }
    }
  }
}

// ---------------- fallback (only if workspace too small) ----------------

__global__ void fallback_kernel(const float* __restrict__ x, const int* __restrict__ w,
                                const float* __restrict__ scale, const float* __restrict__ zero,
                                const float* __restrict__ bias, float* __restrict__ out) {
  const int n = blockIdx.x * 16 + (threadIdx.x & 15);
  const int m = blockIdx.y * 16 + (threadIdx.x >> 4);
  const float z = zero[n];
  const float* xr = x + (size_t)m * K_DIM;
  const int* wr = w + (size_t)n * K_DIM;
  float acc = 0.f;
  for (int k = 0; k < K_DIM; ++k) acc += xr[k] * ((float)wr[k] - z);
  out[(size_t)m * N_DIM + n] = scale[n] * acc + bias[n];
}

// ---------------- launch ----------------

extern "C" void kernel_launch(void* const* d_in, const int* in_sizes, int n_in,
                              void* d_out, int out_size, void* d_ws, size_t ws_size,
                              hipStream_t stream) {
  const float* x     = (const float*)d_in[0];
  const int*   w     = (const int*)d_in[1];
  const float* scale = (const float*)d_in[2];
  const float* zero  = (const float*)d_in[3];
  const float* bias  = (const float*)d_in[4];
  float* out = (float*)d_out;

  const size_t n_x = (size_t)M_DIM * K_DIM;  // 33,554,432
  const size_t n_w = (size_t)N_DIM * K_DIM;  // 45,088,768
  const size_t need = n_x * 2 + n_w + (size_t)M_DIM * 8;  // ~112 MB

  if (ws_size < need) {
    dim3 gr(N_DIM / 16, M_DIM / 16);
    fallback_kernel<<<gr, 256, 0, stream>>>(x, w, scale, zero, bias, out);
    return;
  }

  int8_t* x_h = (int8_t*)d_ws;
  int8_t* x_l = x_h + n_x;
  int8_t* w_q = x_l + n_x;
  float* rsum = (float*)(w_q + n_w);
  float* xs   = rsum + M_DIM;

  convert_w_kernel<<<N_DIM / 16, 256, 0, stream>>>(w, w_q);
  quantx_kernel<<<M_DIM / 16, 256, 0, stream>>>(x, x_h, x_l, xs, rsum);

  const int nblocks = (M_DIM / 128) * (N_DIM / 256);  // 64 * 43 = 2752
  qgemm_kernel<<<nblocks, 512, 0, stream>>>(x_h, x_l, w_q, xs, rsum,
                                            scale, zero, bias, out);
}

// Round 8
// 824.796 us; speedup vs baseline: 1.2258x; 1.2258x over previous
//
#include <hip/hip_runtime.h>
#include <stdint.h>

// y[m,o] = sum_k x[m,k]*(W8[o,k]-zero[o])*scale[o] + bias[o], M=8192 N=11008 K=4096.
// x ~= xs_m*(128*h + l) (h,l int8); G = xs_m*(128*Gh + Gl) via two i8 MFMA GEMMs
// sharing B-frags; y = scale*G - scale*zero*rowsum + bias.
// R8: BM=128 BN=128 BK=64, 256 thr (4 waves 2x2), ring-2 LDS 48KB -> 2 blocks/CU.
// Two co-resident blocks anti-phase (independent barriers) so one block's MFMA
// overlaps the other's LDS reads (m114). One lgkm+vmcnt+barrier per tile.
// 64B LDS rows: additive swizzle phys_slot=(g+(row>>1))&3 (2-way = free);
// staging pre-permutes global col by the inverse (global_load_lds is linear).

#define M_DIM 8192
#define N_DIM 11008
#define K_DIM 4096
#define NT    (K_DIM / 64)    // 64 K-tiles
#define BUFB  24576           // per-buffer: Ah 8K | Al 8K | B 8K

typedef __attribute__((ext_vector_type(4))) int i32x4;

// ---------------- prep kernels ----------------

__global__ void convert_w_kernel(const int* __restrict__ w,
                                 int8_t* __restrict__ o, int n4) {
  int idx = blockIdx.x * blockDim.x + threadIdx.x;
  int stride = gridDim.x * blockDim.x;
  for (int i = idx; i < n4; i += stride) {
    int4 v = ((const int4*)w)[i];
    int r = (v.x & 255) | ((v.y & 255) << 8) | ((v.z & 255) << 16) | ((v.w & 255) << 24);
    ((int*)o)[i] = r;
  }
}

__global__ __launch_bounds__(256) void quantx_kernel(
    const float* __restrict__ x, int8_t* __restrict__ h8, int8_t* __restrict__ l8,
    float* __restrict__ xs, float* __restrict__ rsum) {
  const int row = blockIdx.x;
  const int t = threadIdx.x;
  const float4* px = (const float4*)(x + (size_t)row * K_DIM);
  float4 v[4];
  float mx = 0.f, sm = 0.f;
  #pragma unroll
  for (int i = 0; i < 4; ++i) {
    v[i] = px[i * 256 + t];
    mx = fmaxf(mx, fmaxf(fmaxf(fabsf(v[i].x), fabsf(v[i].y)),
                         fmaxf(fabsf(v[i].z), fabsf(v[i].w))));
    sm += v[i].x + v[i].y + v[i].z + v[i].w;
  }
  #pragma unroll
  for (int off = 32; off > 0; off >>= 1) {
    mx = fmaxf(mx, __shfl_down(mx, off));
    sm += __shfl_down(sm, off);
  }
  __shared__ float rmx[4], rsm[4];
  const int wv = t >> 6, ln = t & 63;
  if (ln == 0) { rmx[wv] = mx; rsm[wv] = sm; }
  __syncthreads();
  const float rowmax = fmaxf(fmaxf(rmx[0], rmx[1]), fmaxf(rmx[2], rmx[3]));
  if (t == 0) {
    xs[row] = rowmax > 0.f ? rowmax / 16256.f : 0.f;
    rsum[row] = rsm[0] + rsm[1] + rsm[2] + rsm[3];
  }
  const float inv = rowmax > 0.f ? 16256.f / rowmax : 0.f;
  int* hp = (int*)(h8 + (size_t)row * K_DIM);
  int* lp = (int*)(l8 + (size_t)row * K_DIM);
  #pragma unroll
  for (int i = 0; i < 4; ++i) {
    int q0 = (int)rintf(v[i].x * inv);
    int q1 = (int)rintf(v[i].y * inv);
    int q2 = (int)rintf(v[i].z * inv);
    int q3 = (int)rintf(v[i].w * inv);
    int h0 = (q0 + 64) >> 7, h1 = (q1 + 64) >> 7, h2 = (q2 + 64) >> 7, h3 = (q3 + 64) >> 7;
    int l0 = q0 - (h0 << 7), l1 = q1 - (h1 << 7), l2 = q2 - (h2 << 7), l3 = q3 - (h3 << 7);
    hp[i * 256 + t] = (h0 & 255) | ((h1 & 255) << 8) | ((h2 & 255) << 16) | ((h3 & 255) << 24);
    lp[i * 256 + t] = (l0 & 255) | ((l1 & 255) << 8) | ((l2 & 255) << 16) | ((l3 & 255) << 24);
  }
}

// ---------------- main GEMM ----------------

__device__ __forceinline__ void stage_tile(
    const int8_t* __restrict__ Ah, const int8_t* __restrict__ Al,
    const int8_t* __restrict__ Bw, size_t a_base, size_t b_base,
    int ks, int srow, int scol, int wave, int8_t* buf) {
  // 6 loads x 256 thr x 16B: Ah[128][64], Al[128][64], B[128][64]
  #pragma unroll
  for (int p = 0; p < 2; ++p) {
    const int8_t* g = Ah + a_base + (size_t)(p * 64 + srow) * K_DIM + ks + scol;
    __builtin_amdgcn_global_load_lds((const __attribute__((address_space(1))) void*)g,
        (__attribute__((address_space(3))) void*)(buf + p * 4096 + wave * 1024), 16, 0, 0);
  }
  #pragma unroll
  for (int p = 0; p < 2; ++p) {
    const int8_t* g = Al + a_base + (size_t)(p * 64 + srow) * K_DIM + ks + scol;
    __builtin_amdgcn_global_load_lds((const __attribute__((address_space(1))) void*)g,
        (__attribute__((address_space(3))) void*)(buf + 8192 + p * 4096 + wave * 1024), 16, 0, 0);
  }
  #pragma unroll
  for (int p = 0; p < 2; ++p) {
    const int8_t* g = Bw + b_base + (size_t)(p * 64 + srow) * K_DIM + ks + scol;
    __builtin_amdgcn_global_load_lds((const __attribute__((address_space(1))) void*)g,
        (__attribute__((address_space(3))) void*)(buf + 16384 + p * 4096 + wave * 1024), 16, 0, 0);
  }
}

__global__ __launch_bounds__(256, 2) void qgemm_kernel(
    const int8_t* __restrict__ Ah, const int8_t* __restrict__ Al,
    const int8_t* __restrict__ Bw, const float* __restrict__ xs,
    const float* __restrict__ rowsum, const float* __restrict__ scale,
    const float* __restrict__ zero, const float* __restrict__ bias,
    float* __restrict__ out) {
  __shared__ int8_t smem[2 * BUFB];  // 48 KB -> 2 blocks/CU

  const int tid = threadIdx.x;
  const int wave = tid >> 6;
  const int lane = tid & 63;

  // XCD-chunked + grouped: nwg = 5504 = 8 XCD x 688 (= 8 bm x 86 bn per chunk)
  const int bid = blockIdx.x;
  const int wg = (bid & 7) * 688 + (bid >> 3);
  const int group = wg / 688;
  const int rem = wg % 688;
  const int bm = group * 8 + (rem & 7);  // 0..63 (M/128)
  const int bn = rem >> 3;               // 0..85 (N/128)

  const int wr = wave >> 1;  // 0..1: 64-row half
  const int wc = wave & 1;   // 0..1: 64-col half

  i32x4 acch[4][4], accl[4][4];
  #pragma unroll
  for (int i = 0; i < 4; ++i)
    #pragma unroll
    for (int j = 0; j < 4; ++j) {
      acch[i][j] = (i32x4){0, 0, 0, 0};
      accl[i][j] = (i32x4){0, 0, 0, 0};
    }

  // staging: thread owns phys slot (tid&3) of row (tid>>2) within each 64-row
  // part; it must load logical slot (p - (row>>1))&3, (row>>1)&3 == (tid>>3)&3.
  const int srow = tid >> 2;                                    // 0..63
  const int scol = ((((tid & 3) - ((tid >> 3) & 3)) & 3) << 4); // byte in 64B row
  const size_t a_base = (size_t)(bm * 128) * K_DIM;
  const size_t b_base = (size_t)(bn * 128) * K_DIM;

  // fragment reads: logical slot g = lane>>4; phys = (g + (row>>1))&3 and
  // (row>>1)&3 == (fr>>1)&3 for all fragment rows (mi*16 ≡ 0 mod 8).
  const int fr = lane & 15;
  const int g = lane >> 4;
  const int scA = (((g + (fr >> 1)) & 3) << 4);

  int arow[4], brow[4];
  #pragma unroll
  for (int i = 0; i < 4; ++i) {
    arow[i] = (wr * 64 + i * 16 + fr) * 64 + scA;
    brow[i] = (wc * 64 + i * 16 + fr) * 64 + scA;
  }

  // prologue: stage tile 0, drain, barrier
  stage_tile(Ah, Al, Bw, a_base, b_base, 0, srow, scol, wave, smem);
  asm volatile("s_waitcnt vmcnt(0)" ::: "memory");
  __builtin_amdgcn_s_barrier();

  #pragma unroll 1
  for (int t = 0; t < NT; ++t) {
    const int8_t* buf = smem + (t & 1) * BUFB;
    int8_t* nxt = smem + ((t + 1) & 1) * BUFB;
    const int8_t* ldsAh_ = buf;
    const int8_t* ldsAl_ = buf + 8192;
    const int8_t* ldsB_  = buf + 16384;

    if (t + 1 < NT)
      stage_tile(Ah, Al, Bw, a_base, b_base, (t + 1) * 64, srow, scol, wave, nxt);

    i32x4 af[4][2], bf[4];
    #pragma unroll
    for (int ni = 0; ni < 4; ++ni)
      bf[ni] = *(const i32x4*)(ldsB_ + brow[ni]);
    #pragma unroll
    for (int mi = 0; mi < 4; ++mi) {
      af[mi][0] = *(const i32x4*)(ldsAh_ + arow[mi]);
      af[mi][1] = *(const i32x4*)(ldsAl_ + arow[mi]);
    }

    __builtin_amdgcn_s_setprio(1);
    #pragma unroll
    for (int mi = 0; mi < 4; ++mi)
      #pragma unroll
      for (int ni = 0; ni < 4; ++ni) {
        acch[mi][ni] = __builtin_amdgcn_mfma_i32_16x16x64_i8(af[mi][0], bf[ni], acch[mi][ni], 0, 0, 0);
        accl[mi][ni] = __builtin_amdgcn_mfma_i32_16x16x64_i8(af[mi][1], bf[ni], accl[mi][ni], 0, 0, 0);
      }
    __builtin_amdgcn_s_setprio(0);

    // all tile-t ds_reads landed + tile-t+1 staging landed before buffer swap
    asm volatile("s_waitcnt lgkmcnt(0)" ::: "memory");
    asm volatile("s_waitcnt vmcnt(0)" ::: "memory");
    __builtin_amdgcn_s_barrier();
  }

  // epilogue: G = xs_m*(128*Gh + Gl); y = scale*G - scale*zero*rowsum + bias
  // C/D 16x16 layout: col = lane&15, row = (lane>>4)*4 + j
  const int row0 = bm * 128 + wr * 64;
  const int col0 = bn * 128 + wc * 64;
  float s_[4], sz_[4], b_[4];
  #pragma unroll
  for (int ni = 0; ni < 4; ++ni) {
    const int n = col0 + ni * 16 + fr;
    const float s = scale[n];
    s_[ni] = s;
    sz_[ni] = s * zero[n];
    b_[ni] = bias[n];
  }
  #pragma unroll
  for (int mi = 0; mi < 4; ++mi) {
    #pragma unroll
    for (int j = 0; j < 4; ++j) {
      const int m = row0 + mi * 16 + g * 4 + j;
      const float xsm = xs[m];
      const float rs = rowsum[m];
      float* po = out + (size_t)m * N_DIM + col0;
      #pragma unroll
      for (int ni = 0; ni < 4; ++ni) {
        const float G = xsm * (128.f * (float)acch[mi][ni][j] + (float)accl[mi][ni][j]);
        po[ni * 16 + fr] = s_[ni] * G - sz_[ni] * rs + b_[ni];
      }
    }
  }
}

// ---------------- fallback (only if workspace too small) ----------------

__global__ void fallback_kernel(const float* __restrict__ x, const int* __restrict__ w,
                                const float* __restrict__ scale, const float* __restrict__ zero,
                                const float* __restrict__ bias, float* __restrict__ out) {
  const int n = blockIdx.x * 16 + (threadIdx.x & 15);
  const int m = blockIdx.y * 16 + (threadIdx.x >> 4);
  const float z = zero[n];
  const float* xr = x + (size_t)m * K_DIM;
  const int* wr = w + (size_t)n * K_DIM;
  float acc = 0.f;
  for (int k = 0; k < K_DIM; ++k) acc += xr[k] * ((float)wr[k] - z);
  out[(size_t)m * N_DIM + n] = scale[n] * acc + bias[n];
}

// ---------------- launch ----------------

extern "C" void kernel_launch(void* const* d_in, const int* in_sizes, int n_in,
                              void* d_out, int out_size, void* d_ws, size_t ws_size,
                              hipStream_t stream) {
  const float* x     = (const float*)d_in[0];
  const int*   w     = (const int*)d_in[1];
  const float* scale = (const float*)d_in[2];
  const float* zero  = (const float*)d_in[3];
  const float* bias  = (const float*)d_in[4];
  float* out = (float*)d_out;

  const size_t n_x = (size_t)M_DIM * K_DIM;
  const size_t n_w = (size_t)N_DIM * K_DIM;
  const size_t need = n_x * 2 + n_w + (size_t)M_DIM * 8;  // ~112 MB

  if (ws_size < need) {
    dim3 gr(N_DIM / 16, M_DIM / 16);
    fallback_kernel<<<gr, 256, 0, stream>>>(x, w, scale, zero, bias, out);
    return;
  }

  int8_t* x_h = (int8_t*)d_ws;
  int8_t* x_l = x_h + n_x;
  int8_t* w_8 = x_l + n_x;
  float* rsum = (float*)(w_8 + n_w);
  float* xs   = rsum + M_DIM;

  convert_w_kernel<<<2048, 256, 0, stream>>>(w, w_8, (int)(n_w / 4));
  quantx_kernel<<<M_DIM, 256, 0, stream>>>(x, x_h, x_l, xs, rsum);

  const int nblocks = (M_DIM / 128) * (N_DIM / 128);  // 64 * 86 = 5504
  qgemm_kernel<<<nblocks, 256, 0, stream>>>(x_h, x_l, w_8, xs, rsum,
                                            scale, zero, bias, out);
}

// Round 9
// 764.656 us; speedup vs baseline: 1.3222x; 1.0787x over previous
//
#include <hip/hip_runtime.h>
#include <stdint.h>

// y[m,o] = sum_k x[m,k]*(W8[o,k]-zero[o])*scale[o] + bias[o], M=8192 N=11008 K=4096.
// x ~= xs_m*(128*h + l) (h,l int8); G = xs_m*(128*Gh + Gl) via two i8 MFMA GEMMs
// sharing B-frags; y = scale*G - scale*zero*rowsum + bias.
// R9: intra-wave software pipeline to overlap the LDS-read and MFMA pipes
// (R4-R8 all measured tile = SUM of pipes, 49% MfmaUtil lockstep):
//   RD(kk1) -> sched_barrier -> stageA(t+1) -> MM(kk0) -> stageB(t+1) ->
//   MM(kk1) -> vmcnt(0) (issued ~2600cyc ago, cheap) -> barrier -> RD(kk0,t+1)
// ONE barrier/tile; frag ping-pong sets; 16x16x64 i8 (proven conflict-free
// read pattern under the slot^=(row&7) swizzle via inverse-swizzled source).

#define M_DIM 8192
#define N_DIM 11008
#define K_DIM 4096
#define NT    (K_DIM / 128)   // 32 K-tiles
#define BUFB  65536           // per LDS buffer: Ah 16K | Al 16K | B 32K

typedef __attribute__((ext_vector_type(4))) int i32x4;

// ---------------- prep kernels ----------------

__global__ void convert_w_kernel(const int* __restrict__ w,
                                 int8_t* __restrict__ o, int n4) {
  int idx = blockIdx.x * blockDim.x + threadIdx.x;
  int stride = gridDim.x * blockDim.x;
  for (int i = idx; i < n4; i += stride) {
    int4 v = ((const int4*)w)[i];
    int r = (v.x & 255) | ((v.y & 255) << 8) | ((v.z & 255) << 16) | ((v.w & 255) << 24);
    ((int*)o)[i] = r;
  }
}

__global__ __launch_bounds__(256) void quantx_kernel(
    const float* __restrict__ x, int8_t* __restrict__ h8, int8_t* __restrict__ l8,
    float* __restrict__ xs, float* __restrict__ rsum) {
  const int row = blockIdx.x;
  const int t = threadIdx.x;
  const float4* px = (const float4*)(x + (size_t)row * K_DIM);
  float4 v[4];
  float mx = 0.f, sm = 0.f;
  #pragma unroll
  for (int i = 0; i < 4; ++i) {
    v[i] = px[i * 256 + t];
    mx = fmaxf(mx, fmaxf(fmaxf(fabsf(v[i].x), fabsf(v[i].y)),
                         fmaxf(fabsf(v[i].z), fabsf(v[i].w))));
    sm += v[i].x + v[i].y + v[i].z + v[i].w;
  }
  #pragma unroll
  for (int off = 32; off > 0; off >>= 1) {
    mx = fmaxf(mx, __shfl_down(mx, off));
    sm += __shfl_down(sm, off);
  }
  __shared__ float rmx[4], rsm[4];
  const int wv = t >> 6, ln = t & 63;
  if (ln == 0) { rmx[wv] = mx; rsm[wv] = sm; }
  __syncthreads();
  const float rowmax = fmaxf(fmaxf(rmx[0], rmx[1]), fmaxf(rmx[2], rmx[3]));
  if (t == 0) {
    xs[row] = rowmax > 0.f ? rowmax / 16256.f : 0.f;
    rsum[row] = rsm[0] + rsm[1] + rsm[2] + rsm[3];
  }
  const float inv = rowmax > 0.f ? 16256.f / rowmax : 0.f;
  int* hp = (int*)(h8 + (size_t)row * K_DIM);
  int* lp = (int*)(l8 + (size_t)row * K_DIM);
  #pragma unroll
  for (int i = 0; i < 4; ++i) {
    int q0 = (int)rintf(v[i].x * inv);
    int q1 = (int)rintf(v[i].y * inv);
    int q2 = (int)rintf(v[i].z * inv);
    int q3 = (int)rintf(v[i].w * inv);
    int h0 = (q0 + 64) >> 7, h1 = (q1 + 64) >> 7, h2 = (q2 + 64) >> 7, h3 = (q3 + 64) >> 7;
    int l0 = q0 - (h0 << 7), l1 = q1 - (h1 << 7), l2 = q2 - (h2 << 7), l3 = q3 - (h3 << 7);
    hp[i * 256 + t] = (h0 & 255) | ((h1 & 255) << 8) | ((h2 & 255) << 16) | ((h3 & 255) << 24);
    lp[i * 256 + t] = (l0 & 255) | ((l1 & 255) << 8) | ((l2 & 255) << 16) | ((l3 & 255) << 24);
  }
}

// ---------------- main GEMM ----------------

__device__ __forceinline__ void stage_A(
    const int8_t* __restrict__ Ah, const int8_t* __restrict__ Al,
    size_t a_base, int ks, int srow, int scol, int wave, int8_t* buf) {
  #pragma unroll
  for (int r = 0; r < 2; ++r) {
    const int8_t* g = Ah + a_base + (size_t)(r * 64 + srow) * K_DIM + ks + scol;
    __builtin_amdgcn_global_load_lds((const __attribute__((address_space(1))) void*)g,
        (__attribute__((address_space(3))) void*)(buf + r * 8192 + wave * 1024), 16, 0, 0);
  }
  #pragma unroll
  for (int r = 0; r < 2; ++r) {
    const int8_t* g = Al + a_base + (size_t)(r * 64 + srow) * K_DIM + ks + scol;
    __builtin_amdgcn_global_load_lds((const __attribute__((address_space(1))) void*)g,
        (__attribute__((address_space(3))) void*)(buf + 16384 + r * 8192 + wave * 1024), 16, 0, 0);
  }
}

__device__ __forceinline__ void stage_B(
    const int8_t* __restrict__ Bw, size_t b_base,
    int ks, int srow, int scol, int wave, int8_t* buf) {
  #pragma unroll
  for (int r = 0; r < 4; ++r) {
    const int8_t* g = Bw + b_base + (size_t)(r * 64 + srow) * K_DIM + ks + scol;
    __builtin_amdgcn_global_load_lds((const __attribute__((address_space(1))) void*)g,
        (__attribute__((address_space(3))) void*)(buf + 32768 + r * 8192 + wave * 1024), 16, 0, 0);
  }
}

__global__ __launch_bounds__(512, 2) void qgemm_kernel(
    const int8_t* __restrict__ Ah, const int8_t* __restrict__ Al,
    const int8_t* __restrict__ Bw, const float* __restrict__ xs,
    const float* __restrict__ rowsum, const float* __restrict__ scale,
    const float* __restrict__ zero, const float* __restrict__ bias,
    float* __restrict__ out) {
  extern __shared__ int8_t smem[];  // 2 x 64KB

  const int tid = threadIdx.x;
  const int wave = tid >> 6;
  const int lane = tid & 63;

  // XCD-chunked + grouped mapping: nwg=2752=8*344
  const int bid = blockIdx.x;
  const int wg = (bid & 7) * 344 + (bid >> 3);
  const int group = wg / 344;
  const int rem = wg % 344;
  const int bm = group * 8 + (rem & 7);  // 0..63 (M/128)
  const int bn = rem >> 3;               // 0..42 (N/256)

  const int wr = wave >> 2;  // 0..1: 64-row half of 128
  const int wc = wave & 3;   // 0..3: 64-col quarter of 256

  i32x4 acch[4][4], accl[4][4];
  #pragma unroll
  for (int i = 0; i < 4; ++i)
    #pragma unroll
    for (int j = 0; j < 4; ++j) {
      acch[i][j] = (i32x4){0, 0, 0, 0};
      accl[i][j] = (i32x4){0, 0, 0, 0};
    }

  // staging: thread owns phys slot (tid&7) of row (tid>>3); load global slot
  // (tid&7)^(row&7) so phys = logical ^ (row&7).
  const int srow = tid >> 3;                               // 0..63
  const int scol = (((tid & 7) ^ ((tid >> 3) & 7)) << 4);  // byte offset in 128B row
  const size_t a_base = (size_t)(bm * 128) * K_DIM;
  const size_t b_base = (size_t)((size_t)bn * 256) * K_DIM;

  // fragment reads (16x16x64): logical slot = g (+4 for kk=64);
  // phys col = (slot ^ (fr&7)) — row&7 == fr&7 for all fragment rows.
  const int fr = lane & 15;
  const int g = lane >> 4;
  const int sw = fr & 7;
  const int sc0 = ((g ^ sw) << 4);
  const int sc1 = (((g + 4) ^ sw) << 4);

  int arow[4], brow[4];
  #pragma unroll
  for (int i = 0; i < 4; ++i) {
    arow[i] = (wr * 64 + i * 16 + fr) * 128;
    brow[i] = (wc * 64 + i * 16 + fr) * 128;
  }

#define RD(sc, ldsAh_, ldsAl_, ldsB_, af, bf) do {                       \
    _Pragma("unroll")                                                    \
    for (int ni = 0; ni < 4; ++ni)                                       \
      bf[ni] = *(const i32x4*)((ldsB_) + brow[ni] + (sc));               \
    _Pragma("unroll")                                                    \
    for (int mi = 0; mi < 4; ++mi) {                                     \
      af[mi][0] = *(const i32x4*)((ldsAh_) + arow[mi] + (sc));           \
      af[mi][1] = *(const i32x4*)((ldsAl_) + arow[mi] + (sc));           \
    }                                                                    \
  } while (0)

#define MM(af, bf) do {                                                  \
    __builtin_amdgcn_s_setprio(1);                                       \
    _Pragma("unroll")                                                    \
    for (int mi = 0; mi < 4; ++mi)                                       \
      _Pragma("unroll")                                                  \
      for (int ni = 0; ni < 4; ++ni) {                                   \
        acch[mi][ni] = __builtin_amdgcn_mfma_i32_16x16x64_i8(af[mi][0], bf[ni], acch[mi][ni], 0, 0, 0); \
        accl[mi][ni] = __builtin_amdgcn_mfma_i32_16x16x64_i8(af[mi][1], bf[ni], accl[mi][ni], 0, 0, 0); \
      }                                                                  \
    __builtin_amdgcn_s_setprio(0);                                       \
  } while (0)

  i32x4 afA[4][2], bfA[4], afB[4][2], bfB[4];

  // prologue: stage tile 0, drain, barrier, read kk0 frags into set A
  stage_A(Ah, Al, a_base, 0, srow, scol, wave, smem);
  stage_B(Bw, b_base, 0, srow, scol, wave, smem);
  asm volatile("s_waitcnt vmcnt(0)" ::: "memory");
  __builtin_amdgcn_s_barrier();
  {
    const int8_t* b0 = smem;
    RD(sc0, b0, b0 + 16384, b0 + 32768, afA, bfA);
  }

  #pragma unroll 1
  for (int t = 0; t < NT; ++t) {
    const int8_t* buf = smem + (t & 1) * BUFB;
    int8_t* nxt = smem + ((t + 1) & 1) * BUFB;
    const int8_t* ldsAh_ = buf;
    const int8_t* ldsAl_ = buf + 16384;
    const int8_t* ldsB_  = buf + 32768;
    const bool pf = (t + 1 < NT);
    const int nks = (t + 1) * 128;

    // issue kk1 reads BEFORE kk0's MFMA cluster (lands under MM's ~1300 cyc)
    RD(sc1, ldsAh_, ldsAl_, ldsB_, afB, bfB);
    __builtin_amdgcn_sched_barrier(0);  // pin: reads stay above the MFMAs
    if (pf) stage_A(Ah, Al, a_base, nks, srow, scol, wave, nxt);

    MM(afA, bfA);  // compiler waits only afA/bfA deps (already resident)

    if (pf) stage_B(Bw, b_base, nks, srow, scol, wave, nxt);
    __builtin_amdgcn_sched_barrier(0);

    MM(afB, bfB);  // auto count-based lgkm wait: afB/bfB landed during MM(afA)

    // next buffer fully staged? loads were issued ~1 MFMA cluster ago -> cheap
    asm volatile("s_waitcnt vmcnt(0)" ::: "memory");
    __builtin_amdgcn_s_barrier();  // all waves done reading buf; nxt ready

    if (pf) {
      const int8_t* nAh = nxt;
      const int8_t* nAl = nxt + 16384;
      const int8_t* nB  = nxt + 32768;
      RD(sc0, nAh, nAl, nB, afA, bfA);  // kk0 frags of tile t+1
    }
  }

#undef RD
#undef MM

  // epilogue: G = xs_m*(128*Gh + Gl); y = scale*G - scale*zero*rowsum + bias
  // C/D 16x16: col = lane&15, row = (lane>>4)*4 + j
  const int row0 = bm * 128 + wr * 64;
  const int col0 = bn * 256 + wc * 64;
  float s_[4], sz_[4], b_[4];
  #pragma unroll
  for (int ni = 0; ni < 4; ++ni) {
    const int n = col0 + ni * 16 + fr;
    const float s = scale[n];
    s_[ni] = s;
    sz_[ni] = s * zero[n];
    b_[ni] = bias[n];
  }
  #pragma unroll
  for (int mi = 0; mi < 4; ++mi) {
    #pragma unroll
    for (int j = 0; j < 4; ++j) {
      const int m = row0 + mi * 16 + g * 4 + j;
      const float xsm = xs[m];
      const float rs = rowsum[m];
      float* po = out + (size_t)m * N_DIM + col0;
      #pragma unroll
      for (int ni = 0; ni < 4; ++ni) {
        const float G = xsm * (128.f * (float)acch[mi][ni][j] + (float)accl[mi][ni][j]);
        po[ni * 16 + fr] = s_[ni] * G - sz_[ni] * rs + b_[ni];
      }
    }
  }
}

// ---------------- fallback (only if workspace too small) ----------------

__global__ void fallback_kernel(const float* __restrict__ x, const int* __restrict__ w,
                                const float* __restrict__ scale, const float* __restrict__ zero,
                                const float* __restrict__ bias, float* __restrict__ out) {
  const int n = blockIdx.x * 16 + (threadIdx.x & 15);
  const int m = blockIdx.y * 16 + (threadIdx.x >> 4);
  const float z = zero[n];
  const float* xr = x + (size_t)m * K_DIM;
  const int* wr = w + (size_t)n * K_DIM;
  float acc = 0.f;
  for (int k = 0; k < K_DIM; ++k) acc += xr[k] * ((float)wr[k] - z);
  out[(size_t)m * N_DIM + n] = scale[n] * acc + bias[n];
}

// ---------------- launch ----------------

extern "C" void kernel_launch(void* const* d_in, const int* in_sizes, int n_in,
                              void* d_out, int out_size, void* d_ws, size_t ws_size,
                              hipStream_t stream) {
  const float* x     = (const float*)d_in[0];
  const int*   w     = (const int*)d_in[1];
  const float* scale = (const float*)d_in[2];
  const float* zero  = (const float*)d_in[3];
  const float* bias  = (const float*)d_in[4];
  float* out = (float*)d_out;

  const size_t n_x = (size_t)M_DIM * K_DIM;
  const size_t n_w = (size_t)N_DIM * K_DIM;
  const size_t need = n_x * 2 + n_w + (size_t)M_DIM * 8;  // ~112 MB

  if (ws_size < need) {
    dim3 gr(N_DIM / 16, M_DIM / 16);
    fallback_kernel<<<gr, 256, 0, stream>>>(x, w, scale, zero, bias, out);
    return;
  }

  int8_t* x_h = (int8_t*)d_ws;
  int8_t* x_l = x_h + n_x;
  int8_t* w_8 = x_l + n_x;
  float* rsum = (float*)(w_8 + n_w);
  float* xs   = rsum + M_DIM;

  convert_w_kernel<<<2048, 256, 0, stream>>>(w, w_8, (int)(n_w / 4));
  quantx_kernel<<<M_DIM, 256, 0, stream>>>(x, x_h, x_l, xs, rsum);

  (void)hipFuncSetAttribute((const void*)qgemm_kernel,
                            hipFuncAttributeMaxDynamicSharedMemorySize, 2 * BUFB);

  const int nblocks = (M_DIM / 128) * (N_DIM / 256);  // 64 * 43 = 2752
  qgemm_kernel<<<nblocks, 512, 2 * BUFB, stream>>>(x_h, x_l, w_8, xs, rsum,
                                                   scale, zero, bias, out);
}